// Round 3
// baseline (1031.276 us; speedup 1.0000x reference)
//
#include <hip/hip_runtime.h>

typedef unsigned short u16;
typedef __bf16 v8bf __attribute__((ext_vector_type(8)));
typedef unsigned short u16x8 __attribute__((ext_vector_type(8)));
typedef float v4f __attribute__((ext_vector_type(4)));

#define DEV __device__ __forceinline__

constexpr int M_TOK = 512 * 77;   // 39424 = 256*154

DEV u16 f2bf(float f) {
  union { float f; unsigned int u; } v; v.f = f;
  unsigned int r = v.u + 0x7fffu + ((v.u >> 16) & 1u);
  return (u16)(r >> 16);
}

DEV void gload16(const void* g, void* l) {
  __builtin_amdgcn_global_load_lds((const __attribute__((address_space(1))) void*)g,
                                   (__attribute__((address_space(3))) void*)l, 16, 0, 0);
}

DEV v4f MF(v8bf a, v8bf b, v4f c) {
  return __builtin_amdgcn_mfma_f32_16x16x32_bf16(a, b, c, 0, 0, 0);
}

// ---------------- fp32 -> bf16 convert (x4 vectorized), optional scale ----------------
__global__ void cvt4_k(const float* __restrict__ src, u16* __restrict__ dst, int n4, float scale) {
  int i = blockIdx.x * blockDim.x + threadIdx.x;
  if (i >= n4) return;
  const float4 v = ((const float4*)src)[i];
  ushort4 o;
  o.x = f2bf(v.x * scale); o.y = f2bf(v.y * scale);
  o.z = f2bf(v.z * scale); o.w = f2bf(v.w * scale);
  ((ushort4*)dst)[i] = o;
}

__global__ void qkvb_k(const float* __restrict__ qb, const float* __restrict__ kb,
                       const float* __restrict__ vb, float* __restrict__ dst) {
  int i = blockIdx.x * 256 + threadIdx.x;
  if (i >= 2304) return;
  dst[i] = (i < 768) ? qb[i] * 0.125f : (i < 1536 ? kb[i - 768] : vb[i - 1536]);
}

// ---------------- LayerNorm: one wave per row of 768, writes bf16 ----------------
__global__ __launch_bounds__(256) void ln_k(const float* __restrict__ x, const float* __restrict__ w,
                                            const float* __restrict__ bvec, u16* __restrict__ out, int nrows) {
  const int lane = threadIdx.x & 63;
  const int row = blockIdx.x * 4 + (threadIdx.x >> 6);
  if (row >= nrows) return;
  const float4* xr = (const float4*)(x + (size_t)row * 768);
  float4 v[3];
  float sum = 0.f, sq = 0.f;
#pragma unroll
  for (int t = 0; t < 3; ++t) {
    v[t] = xr[lane + 64 * t];
    sum += v[t].x + v[t].y + v[t].z + v[t].w;
    sq  += v[t].x * v[t].x + v[t].y * v[t].y + v[t].z * v[t].z + v[t].w * v[t].w;
  }
#pragma unroll
  for (int o = 1; o < 64; o <<= 1) { sum += __shfl_xor(sum, o, 64); sq += __shfl_xor(sq, o, 64); }
  const float mean = sum * (1.f / 768.f);
  const float inv = rsqrtf(sq * (1.f / 768.f) - mean * mean + 1e-5f);
  u16* orow = out + (size_t)row * 768;
#pragma unroll
  for (int t = 0; t < 3; ++t) {
    const int c = 4 * (lane + 64 * t);
    ushort4 o4;
    o4.x = f2bf((v[t].x - mean) * inv * w[c + 0] + bvec[c + 0]);
    o4.y = f2bf((v[t].y - mean) * inv * w[c + 1] + bvec[c + 1]);
    o4.z = f2bf((v[t].z - mean) * inv * w[c + 2] + bvec[c + 2]);
    o4.w = f2bf((v[t].w - mean) * inv * w[c + 3] + bvec[c + 3]);
    *(ushort4*)(orow + c) = o4;
  }
}

// ---------------- GEMM 256x256 tile, BK=32, 8 waves, 4-deep LDS ring, counted vmcnt ----
// out[M][N] = act(A[M][K](bf16) @ B[N][K]^T(bf16) + bias) [+res]
// Block mapping: n-OUTER, m-inner (m = blockIdx % nbm). Consecutive blockIdx round-robin
// the 8 XCDs within one n-column: B-block stays L2-resident per XCD, and all XCDs
// stream the same A m-window in lockstep (A served from L3 after first touch).
template <int OUTF32, int ACT, int RES>
__global__ __launch_bounds__(512, 2) void gemm256_k(
    const u16* __restrict__ A, const u16* __restrict__ Bw,
    const float* __restrict__ bias, const float* __restrict__ res,
    void* __restrict__ out, int M, int N, int K, int nbx) {
  __shared__ u16 lds[65536];
  const int tid = threadIdx.x;
  const int lane = tid & 63;
  const int wv = tid >> 6;
  const int wr = wv >> 2, wc = wv & 3;   // wave tile: 128(M) x 64(N)

  const int nbm = gridDim.x / nbx;       // = M/256 = 154
  const int m0 = (blockIdx.x % nbm) * 256;
  const int n0 = (blockIdx.x / nbm) * 256;

  const int frow = lane & 15;
  const int fq = lane >> 4;
  const int chunkp = (fq ^ (lane & 3) ^ ((lane >> 2) & 3)) & 3;  // cw ^ s(R), s depends only on frow
  const int aRd = (wr * 128 + frow) * 32 + chunkp * 8;           // u16 index in A region
  const int bRd = (wc * 64 + frow) * 32 + chunkp * 8;            // u16 index in B region

  // staging: thread tid stages 16B of row (g*128 + tid>>2), global chunk pre-swizzled
  const int srow = tid >> 2;
  const int scg = ((tid & 3) ^ (srow & 3) ^ ((srow >> 2) & 3)) & 3;
  const size_t aBase = (size_t)(m0 + srow) * K + scg * 8;
  const size_t bBase = (size_t)(n0 + srow) * K + scg * 8;
  const int ldsW = wv * 512;   // wave-uniform dest; HW adds lane*16B

#define GLDA(kt, g) gload16(A + aBase + (size_t)(g) * 128 * K + (kt) * 32, \
                            &lds[(((kt) & 3) << 14) + ((g) << 12) + ldsW])
#define GLDB(kt, g) gload16(Bw + bBase + (size_t)(g) * 128 * K + (kt) * 32, \
                            &lds[(((kt) & 3) << 14) + 8192 + ((g) << 12) + ldsW])
#define BAR() asm volatile("s_barrier" ::: "memory")

  v4f acc[8][4];
#pragma unroll
  for (int i = 0; i < 8; ++i)
#pragma unroll
    for (int j = 0; j < 4; ++j) acc[i][j] = (v4f){0.f, 0.f, 0.f, 0.f};

  const int NT = K >> 5;   // 24 or 96; NT >= 4, NT % 4 == 0

  // prologue: stage tiles 0,1,2 (12 loads); wait tile 0 (keep 8 in flight)
  GLDA(0, 0); GLDA(0, 1); GLDB(0, 0); GLDB(0, 1);
  GLDA(1, 0); GLDA(1, 1); GLDB(1, 0); GLDB(1, 1);
  GLDA(2, 0); GLDA(2, 1); GLDB(2, 0); GLDB(2, 1);
  asm volatile("s_waitcnt vmcnt(8)" ::: "memory");
  BAR();

  // K-tile body: phase1 = acc rows 0-3 (reads A0-3 + B0-3, stages A of kt+3),
  //              phase2 = acc rows 4-7 (reads A4-7, stages B of kt+3, counted vmcnt)
#define KTILE(kt, STG, VM)                                                      \
  do {                                                                          \
    const int sb = ((kt) & 3) << 14;                                            \
    v8bf fa0 = *(const v8bf*)&lds[sb + aRd +    0];                             \
    v8bf fa1 = *(const v8bf*)&lds[sb + aRd +  512];                             \
    v8bf fa2 = *(const v8bf*)&lds[sb + aRd + 1024];                             \
    v8bf fa3 = *(const v8bf*)&lds[sb + aRd + 1536];                             \
    v8bf fb0 = *(const v8bf*)&lds[sb + 8192 + bRd +    0];                      \
    v8bf fb1 = *(const v8bf*)&lds[sb + 8192 + bRd +  512];                      \
    v8bf fb2 = *(const v8bf*)&lds[sb + 8192 + bRd + 1024];                      \
    v8bf fb3 = *(const v8bf*)&lds[sb + 8192 + bRd + 1536];                      \
    if (STG) { GLDA((kt) + 3, 0); GLDA((kt) + 3, 1); }                          \
    BAR();                                                                      \
    __builtin_amdgcn_s_setprio(1);                                              \
    acc[0][0] = MF(fa0, fb0, acc[0][0]); acc[0][1] = MF(fa0, fb1, acc[0][1]);   \
    acc[0][2] = MF(fa0, fb2, acc[0][2]); acc[0][3] = MF(fa0, fb3, acc[0][3]);   \
    acc[1][0] = MF(fa1, fb0, acc[1][0]); acc[1][1] = MF(fa1, fb1, acc[1][1]);   \
    acc[1][2] = MF(fa1, fb2, acc[1][2]); acc[1][3] = MF(fa1, fb3, acc[1][3]);   \
    acc[2][0] = MF(fa2, fb0, acc[2][0]); acc[2][1] = MF(fa2, fb1, acc[2][1]);   \
    acc[2][2] = MF(fa2, fb2, acc[2][2]); acc[2][3] = MF(fa2, fb3, acc[2][3]);   \
    acc[3][0] = MF(fa3, fb0, acc[3][0]); acc[3][1] = MF(fa3, fb1, acc[3][1]);   \
    acc[3][2] = MF(fa3, fb2, acc[3][2]); acc[3][3] = MF(fa3, fb3, acc[3][3]);   \
    __builtin_amdgcn_s_setprio(0);                                              \
    BAR();                                                                      \
    v8bf fa4 = *(const v8bf*)&lds[sb + aRd + 2048];                             \
    v8bf fa5 = *(const v8bf*)&lds[sb + aRd + 2560];                             \
    v8bf fa6 = *(const v8bf*)&lds[sb + aRd + 3072];                             \
    v8bf fa7 = *(const v8bf*)&lds[sb + aRd + 3584];                             \
    if (STG) { GLDB((kt) + 3, 0); GLDB((kt) + 3, 1); }                          \
    if ((VM) == 8) asm volatile("s_waitcnt vmcnt(8)" ::: "memory");             \
    else if ((VM) == 4) asm volatile("s_waitcnt vmcnt(4)" ::: "memory");        \
    else if ((VM) == 0) asm volatile("s_waitcnt vmcnt(0)" ::: "memory");        \
    BAR();                                                                      \
    __builtin_amdgcn_s_setprio(1);                                              \
    acc[4][0] = MF(fa4, fb0, acc[4][0]); acc[4][1] = MF(fa4, fb1, acc[4][1]);   \
    acc[4][2] = MF(fa4, fb2, acc[4][2]); acc[4][3] = MF(fa4, fb3, acc[4][3]);   \
    acc[5][0] = MF(fa5, fb0, acc[5][0]); acc[5][1] = MF(fa5, fb1, acc[5][1]);   \
    acc[5][2] = MF(fa5, fb2, acc[5][2]); acc[5][3] = MF(fa5, fb3, acc[5][3]);   \
    acc[6][0] = MF(fa6, fb0, acc[6][0]); acc[6][1] = MF(fa6, fb1, acc[6][1]);   \
    acc[6][2] = MF(fa6, fb2, acc[6][2]); acc[6][3] = MF(fa6, fb3, acc[6][3]);   \
    acc[7][0] = MF(fa7, fb0, acc[7][0]); acc[7][1] = MF(fa7, fb1, acc[7][1]);   \
    acc[7][2] = MF(fa7, fb2, acc[7][2]); acc[7][3] = MF(fa7, fb3, acc[7][3]);   \
    __builtin_amdgcn_s_setprio(0);                                              \
    BAR();                                                                      \
  } while (0)

  for (int kt = 0; kt + 3 < NT; ++kt) KTILE(kt, 1, 8);
  KTILE(NT - 3, 0, 4);
  KTILE(NT - 2, 0, 0);
  KTILE(NT - 1, 0, -1);
#undef KTILE
#undef GLDA
#undef GLDB
#undef BAR

  // epilogue: C/D layout col=lane&15, row=(lane>>4)*4+rr
#pragma unroll
  for (int i = 0; i < 8; ++i) {
    const int rowb = m0 + wr * 128 + i * 16 + fq * 4;
#pragma unroll
    for (int j = 0; j < 4; ++j) {
      const int col = n0 + wc * 64 + j * 16 + frow;
      const float bv = bias[col];
#pragma unroll
      for (int rr = 0; rr < 4; ++rr) {
        float v = acc[i][j][rr] + bv;
        if (ACT) v = v * (1.f / (1.f + __expf(-1.702f * v)));  // QuickGELU
        const size_t off = (size_t)(rowb + rr) * N + col;
        if (RES) v += res[off];
        if (OUTF32) ((float*)out)[off] = v;
        else ((u16*)out)[off] = f2bf(v);
      }
    }
  }
}

// ---------------- attention: one block per (b,h); S=77 padded to 80 ----------------
__global__ __launch_bounds__(256) void attn_k(const u16* __restrict__ qkv, u16* __restrict__ ctx) {
  __shared__ u16 sQK[10240];        // sQ[80][64] @0, sK[80][64] @5120; later reused as sP[80][96]
  __shared__ u16 sVt[64 * 120];     // V transposed [d][k], stride 120
  __shared__ float sS[80][81];      // scores fp32
  const int tid = threadIdx.x;
  const int lane = tid & 63;
  const int wv = tid >> 6;
  const int b = blockIdx.x / 12;
  const int h = blockIdx.x % 12;
  u16* sQ = sQK;
  u16* sK = sQK + 5120;
  u16* sP = sQK;

  for (int i = tid; i < 10240 + 64 * 120; i += 256) {
    if (i < 10240) sQK[i] = 0; else sVt[i - 10240] = 0;
  }
  __syncthreads();

  const size_t tokBase = (size_t)(b * 77) * 2304 + h * 64;
  for (int c = tid; c < 77 * 8; c += 256) {
    const int row = c >> 3, k8 = (c & 7) * 8;
    const size_t src = tokBase + (size_t)row * 2304 + k8;
    *(u16x8*)&sQ[row * 64 + k8] = *(const u16x8*)&qkv[src];
    *(u16x8*)&sK[row * 64 + k8] = *(const u16x8*)&qkv[src + 768];
    u16x8 v = *(const u16x8*)&qkv[src + 1536];
#pragma unroll
    for (int j = 0; j < 8; ++j) sVt[(k8 + j) * 120 + row] = v[j];
  }
  __syncthreads();

  const int frow = lane & 15, fk = (lane >> 4) * 8;
  for (int t = wv; t < 25; t += 4) {
    const int it = t / 5, jt = t % 5;
    v4f acc = {0.f, 0.f, 0.f, 0.f};
#pragma unroll
    for (int kk = 0; kk < 2; ++kk) {
      v8bf a = *(const v8bf*)&sQ[(it * 16 + frow) * 64 + kk * 32 + fk];
      v8bf bb = *(const v8bf*)&sK[(jt * 16 + frow) * 64 + kk * 32 + fk];
      acc = MF(a, bb, acc);
    }
    const int col = jt * 16 + frow;
#pragma unroll
    for (int r = 0; r < 4; ++r) {
      const int row = it * 16 + (lane >> 4) * 4 + r;
      sS[row][col] = (col > row) ? -1e30f : acc[r];
    }
  }
  __syncthreads();

  if (tid < 80) {
    const int row = tid;
    float mx = -1e30f;
    for (int c2 = 0; c2 < 80; ++c2) mx = fmaxf(mx, sS[row][c2]);
    float sum = 0.f;
    for (int c2 = 0; c2 < 80; ++c2) { float e = __expf(sS[row][c2] - mx); sum += e; sS[row][c2] = e; }
    const float inv = 1.f / sum;
    for (int c2 = 0; c2 < 80; ++c2) sP[row * 96 + c2] = f2bf(sS[row][c2] * inv);
    for (int c2 = 80; c2 < 96; ++c2) sP[row * 96 + c2] = 0;
  }
  __syncthreads();

  const size_t outBase = (size_t)(b * 77) * 768 + h * 64;
  for (int t = wv; t < 20; t += 4) {
    const int it = t / 4, jt = t % 4;
    v4f acc = {0.f, 0.f, 0.f, 0.f};
#pragma unroll
    for (int kk = 0; kk < 3; ++kk) {
      v8bf a = *(const v8bf*)&sP[(it * 16 + frow) * 96 + kk * 32 + fk];
      v8bf bb = *(const v8bf*)&sVt[(jt * 16 + frow) * 120 + kk * 32 + fk];
      acc = MF(a, bb, acc);
    }
    const int col = jt * 16 + frow;
#pragma unroll
    for (int r = 0; r < 4; ++r) {
      const int row = it * 16 + (lane >> 4) * 4 + r;
      if (row < 77) ctx[outBase + (size_t)row * 768 + col] = f2bf(acc[r]);
    }
  }
}

// ---------------- launch ----------------
extern "C" void kernel_launch(void* const* d_in, const int* in_sizes, int n_in,
                              void* d_out, int out_size, void* d_ws, size_t ws_size,
                              hipStream_t stream) {
  const float* x    = (const float*)d_in[0];
  const float* ln1w = (const float*)d_in[1];
  const float* ln1b = (const float*)d_in[2];
  const float* qw   = (const float*)d_in[3];
  const float* qb   = (const float*)d_in[4];
  const float* kw   = (const float*)d_in[5];
  const float* kb   = (const float*)d_in[6];
  const float* vw   = (const float*)d_in[7];
  const float* vb   = (const float*)d_in[8];
  const float* ow   = (const float*)d_in[9];
  const float* ob   = (const float*)d_in[10];
  const float* ln2w = (const float*)d_in[11];
  const float* ln2b = (const float*)d_in[12];
  const float* f1wf = (const float*)d_in[13];
  const float* f1b  = (const float*)d_in[14];
  const float* f2wf = (const float*)d_in[15];
  const float* f2b  = (const float*)d_in[16];
  float* outp = (float*)d_out;

  char* p = (char*)d_ws;
  auto alloc = [&](size_t bytes) { char* r = p; p += (bytes + 255) & ~(size_t)255; return r; };
  u16* wqkv = (u16*)alloc((size_t)2304 * 768 * 2);   // rows: qw*0.125 | kw | vw
  u16* owb  = (u16*)alloc((size_t)768 * 768 * 2);
  u16* f1w  = (u16*)alloc((size_t)3072 * 768 * 2);
  u16* f2w  = (u16*)alloc((size_t)768 * 3072 * 2);
  float* qkvb = (float*)alloc(2304 * 4);
  u16* bufA = (u16*)alloc((size_t)M_TOK * 768 * 2);   // h -> ctx -> h2in
  u16* bufB = (u16*)alloc((size_t)M_TOK * 3072 * 2);  // qkv (2304 cols) -> h2 (3072 cols)

  cvt4_k<<<576, 256, 0, stream>>>(qw, wqkv, 147456, 0.125f);
  cvt4_k<<<576, 256, 0, stream>>>(kw, wqkv + 589824, 147456, 1.f);
  cvt4_k<<<576, 256, 0, stream>>>(vw, wqkv + 1179648, 147456, 1.f);
  cvt4_k<<<576, 256, 0, stream>>>(ow, owb, 147456, 1.f);
  cvt4_k<<<2304, 256, 0, stream>>>(f1wf, f1w, 589824, 1.f);
  cvt4_k<<<2304, 256, 0, stream>>>(f2wf, f2w, 589824, 1.f);
  qkvb_k<<<9, 256, 0, stream>>>(qb, kb, vb, qkvb);

  ln_k<<<M_TOK / 4, 256, 0, stream>>>(x, ln1w, ln1b, bufA, M_TOK);
  gemm256_k<0, 0, 0><<<154 * 9, 512, 0, stream>>>(bufA, wqkv, qkvb, nullptr, bufB, M_TOK, 2304, 768, 9);
  attn_k<<<512 * 12, 256, 0, stream>>>(bufB, bufA);
  gemm256_k<1, 0, 1><<<154 * 3, 512, 0, stream>>>(bufA, owb, ob, x, outp, M_TOK, 768, 768, 3);
  ln_k<<<M_TOK / 4, 256, 0, stream>>>(outp, ln2w, ln2b, bufA, M_TOK);
  gemm256_k<0, 1, 0><<<154 * 12, 512, 0, stream>>>(bufA, f1w, f1b, nullptr, bufB, M_TOK, 3072, 768, 12);
  gemm256_k<1, 0, 1><<<154 * 3, 512, 0, stream>>>(bufB, f2w, f2b, outp, outp, M_TOK, 768, 3072, 3);
}

// Round 4
// 967.514 us; speedup vs baseline: 1.0659x; 1.0659x over previous
//
#include <hip/hip_runtime.h>

typedef unsigned short u16;
typedef __bf16 v8bf __attribute__((ext_vector_type(8)));
typedef unsigned short u16x8 __attribute__((ext_vector_type(8)));
typedef float v4f __attribute__((ext_vector_type(4)));

#define DEV __device__ __forceinline__

constexpr int M_TOK = 512 * 77;   // 39424 = 128*308

DEV u16 f2bf(float f) {
  union { float f; unsigned int u; } v; v.f = f;
  unsigned int r = v.u + 0x7fffu + ((v.u >> 16) & 1u);
  return (u16)(r >> 16);
}

DEV void gload16(const void* g, void* l) {
  __builtin_amdgcn_global_load_lds((const __attribute__((address_space(1))) void*)g,
                                   (__attribute__((address_space(3))) void*)l, 16, 0, 0);
}

DEV v4f MF(v8bf a, v8bf b, v4f c) {
  return __builtin_amdgcn_mfma_f32_16x16x32_bf16(a, b, c, 0, 0, 0);
}

// ---------------- fp32 -> bf16 convert (x4 vectorized), optional scale ----------------
__global__ void cvt4_k(const float* __restrict__ src, u16* __restrict__ dst, int n4, float scale) {
  int i = blockIdx.x * blockDim.x + threadIdx.x;
  if (i >= n4) return;
  const float4 v = ((const float4*)src)[i];
  ushort4 o;
  o.x = f2bf(v.x * scale); o.y = f2bf(v.y * scale);
  o.z = f2bf(v.z * scale); o.w = f2bf(v.w * scale);
  ((ushort4*)dst)[i] = o;
}

__global__ void qkvb_k(const float* __restrict__ qb, const float* __restrict__ kb,
                       const float* __restrict__ vb, float* __restrict__ dst) {
  int i = blockIdx.x * 256 + threadIdx.x;
  if (i >= 2304) return;
  dst[i] = (i < 768) ? qb[i] * 0.125f : (i < 1536 ? kb[i - 768] : vb[i - 1536]);
}

// ---------------- LayerNorm: one wave per row of 768, writes bf16 ----------------
__global__ __launch_bounds__(256) void ln_k(const float* __restrict__ x, const float* __restrict__ w,
                                            const float* __restrict__ bvec, u16* __restrict__ out, int nrows) {
  const int lane = threadIdx.x & 63;
  const int row = blockIdx.x * 4 + (threadIdx.x >> 6);
  if (row >= nrows) return;
  const float4* xr = (const float4*)(x + (size_t)row * 768);
  float4 v[3];
  float sum = 0.f, sq = 0.f;
#pragma unroll
  for (int t = 0; t < 3; ++t) {
    v[t] = xr[lane + 64 * t];
    sum += v[t].x + v[t].y + v[t].z + v[t].w;
    sq  += v[t].x * v[t].x + v[t].y * v[t].y + v[t].z * v[t].z + v[t].w * v[t].w;
  }
#pragma unroll
  for (int o = 1; o < 64; o <<= 1) { sum += __shfl_xor(sum, o, 64); sq += __shfl_xor(sq, o, 64); }
  const float mean = sum * (1.f / 768.f);
  const float inv = rsqrtf(sq * (1.f / 768.f) - mean * mean + 1e-5f);
  u16* orow = out + (size_t)row * 768;
#pragma unroll
  for (int t = 0; t < 3; ++t) {
    const int c = 4 * (lane + 64 * t);
    ushort4 o4;
    o4.x = f2bf((v[t].x - mean) * inv * w[c + 0] + bvec[c + 0]);
    o4.y = f2bf((v[t].y - mean) * inv * w[c + 1] + bvec[c + 1]);
    o4.z = f2bf((v[t].z - mean) * inv * w[c + 2] + bvec[c + 2]);
    o4.w = f2bf((v[t].w - mean) * inv * w[c + 3] + bvec[c + 3]);
    *(ushort4*)(orow + c) = o4;
  }
}

// ---------------- GEMM 128x256 tile, BK=32, 8 waves (64x64 each), 2-slot LDS ring ----
// out[M][N] = act(A[M][K](bf16) @ B[N][K]^T(bf16) + bias) [+res]
// LDS slot = A[128][32] (8KB) + B[256][32] (16KB) = 24KB; 2 slots = 48KB -> 2 blocks/CU.
// Registers: acc 64 + frags 32 + addr ~20 -> fits 128 (launch_bounds(512,4) = 4 waves/EU).
// Per K-tile: ds_read x8 -> lgkmcnt(0) -> barrier -> stage kt+2 (3 loads) -> vmcnt(3)
//             -> 16 MFMA -> barrier.  Counted vmcnt, never drained mid-loop.
template <int OUTF32, int ACT, int RES>
__global__ __launch_bounds__(512, 4) void gemm_k(
    const u16* __restrict__ A, const u16* __restrict__ Bw,
    const float* __restrict__ bias, const float* __restrict__ res,
    void* __restrict__ out, int M, int N, int K, int nbx) {
  __shared__ u16 lds[24576];   // 2 slots x 12288 u16
  const int tid = threadIdx.x;
  const int lane = tid & 63;
  const int wv = tid >> 6;
  const int wr = wv >> 2, wc = wv & 3;   // wave tile: 64(M) x 64(N)

  // bijective XCD swizzle (m204 form), m-outer enumeration (round-2 proven lowest FETCH)
  const int nwg = gridDim.x;
  const int q = nwg >> 3, r8 = nwg & 7;
  const int xcd = blockIdx.x & 7, cidx = blockIdx.x >> 3;
  const int wg = (xcd < r8 ? xcd * (q + 1) : r8 * (q + 1) + (xcd - r8) * q) + cidx;
  const int m0 = (wg / nbx) * 128;
  const int n0 = (wg % nbx) * 256;

  const int frow = lane & 15;
  const int fq = lane >> 4;
  const int chunkp = (fq ^ (lane & 3) ^ ((lane >> 2) & 3)) & 3;  // global chunk fq at row frow
  const int aRd = (wr * 64 + frow) * 32 + chunkp * 8;            // u16 index in A region
  const int bRd = 4096 + (wc * 64 + frow) * 32 + chunkp * 8;     // u16 index in B region

  // staging: thread tid stages 16B of row (tid>>2) [A] / (g*128 + tid>>2) [B]
  const int srow = tid >> 2;
  const int scg = ((tid & 3) ^ (srow & 3) ^ ((srow >> 2) & 3)) & 3;
  const size_t aBase = (size_t)(m0 + srow) * K + scg * 8;
  const size_t bBase = (size_t)(n0 + srow) * K + scg * 8;
  const int ldsW = wv * 512;   // wave-uniform dest; HW adds lane*16B

#define GLDA(kt) gload16(A + aBase + (size_t)(kt) * 32, \
                         &lds[(((kt) & 1) ? 12288 : 0) + ldsW])
#define GLDB(kt, g) gload16(Bw + bBase + (size_t)(g) * 128 * K + (size_t)(kt) * 32, \
                            &lds[(((kt) & 1) ? 12288 : 0) + 4096 + ((g) << 12) + ldsW])
#define BAR() asm volatile("s_barrier" ::: "memory")

  v4f acc[4][4];
#pragma unroll
  for (int i = 0; i < 4; ++i)
#pragma unroll
    for (int j = 0; j < 4; ++j) acc[i][j] = (v4f){0.f, 0.f, 0.f, 0.f};

  const int NT = K >> 5;   // 24 or 96

  // prologue: stage tiles 0,1 (6 loads); wait tile 0 (keep tile 1's 3 in flight)
  GLDA(0); GLDB(0, 0); GLDB(0, 1);
  GLDA(1); GLDB(1, 0); GLDB(1, 1);
  asm volatile("s_waitcnt vmcnt(3)" ::: "memory");
  BAR();

#define KTILE(kt, STG, VM)                                                      \
  do {                                                                          \
    const int sb = ((kt) & 1) ? 12288 : 0;                                      \
    v8bf fa0 = *(const v8bf*)&lds[sb + aRd +    0];                             \
    v8bf fa1 = *(const v8bf*)&lds[sb + aRd +  512];                             \
    v8bf fa2 = *(const v8bf*)&lds[sb + aRd + 1024];                             \
    v8bf fa3 = *(const v8bf*)&lds[sb + aRd + 1536];                             \
    v8bf fb0 = *(const v8bf*)&lds[sb + bRd +    0];                             \
    v8bf fb1 = *(const v8bf*)&lds[sb + bRd +  512];                             \
    v8bf fb2 = *(const v8bf*)&lds[sb + bRd + 1024];                             \
    v8bf fb3 = *(const v8bf*)&lds[sb + bRd + 1536];                             \
    asm volatile("s_waitcnt lgkmcnt(0)" ::: "memory");                          \
    BAR();  /* all waves finished reading slot -> safe to overwrite */          \
    if (STG) { GLDA((kt) + 2); GLDB((kt) + 2, 0); GLDB((kt) + 2, 1); }          \
    if ((VM) == 3) asm volatile("s_waitcnt vmcnt(3)" ::: "memory");             \
    else if ((VM) == 0) asm volatile("s_waitcnt vmcnt(0)" ::: "memory");        \
    __builtin_amdgcn_s_setprio(1);                                              \
    acc[0][0] = MF(fa0, fb0, acc[0][0]); acc[0][1] = MF(fa0, fb1, acc[0][1]);   \
    acc[0][2] = MF(fa0, fb2, acc[0][2]); acc[0][3] = MF(fa0, fb3, acc[0][3]);   \
    acc[1][0] = MF(fa1, fb0, acc[1][0]); acc[1][1] = MF(fa1, fb1, acc[1][1]);   \
    acc[1][2] = MF(fa1, fb2, acc[1][2]); acc[1][3] = MF(fa1, fb3, acc[1][3]);   \
    acc[2][0] = MF(fa2, fb0, acc[2][0]); acc[2][1] = MF(fa2, fb1, acc[2][1]);   \
    acc[2][2] = MF(fa2, fb2, acc[2][2]); acc[2][3] = MF(fa2, fb3, acc[2][3]);   \
    acc[3][0] = MF(fa3, fb0, acc[3][0]); acc[3][1] = MF(fa3, fb1, acc[3][1]);   \
    acc[3][2] = MF(fa3, fb2, acc[3][2]); acc[3][3] = MF(fa3, fb3, acc[3][3]);   \
    __builtin_amdgcn_s_setprio(0);                                              \
    BAR();  /* all waves passed vmcnt -> slot (kt+1) fully staged */            \
  } while (0)

  for (int kt = 0; kt < NT - 2; ++kt) KTILE(kt, 1, 3);
  KTILE(NT - 2, 0, 0);
  KTILE(NT - 1, 0, -1);
#undef KTILE
#undef GLDA
#undef GLDB
#undef BAR

  // epilogue: C/D layout col=lane&15, row=(lane>>4)*4+rr
#pragma unroll
  for (int i = 0; i < 4; ++i) {
    const int rowb = m0 + wr * 64 + i * 16 + fq * 4;
#pragma unroll
    for (int j = 0; j < 4; ++j) {
      const int col = n0 + wc * 64 + j * 16 + frow;
      const float bv = bias[col];
#pragma unroll
      for (int rr = 0; rr < 4; ++rr) {
        float v = acc[i][j][rr] + bv;
        if (ACT) v = v * (1.f / (1.f + __expf(-1.702f * v)));  // QuickGELU
        const size_t off = (size_t)(rowb + rr) * N + col;
        if (RES) v += res[off];
        if (OUTF32) ((float*)out)[off] = v;
        else ((u16*)out)[off] = f2bf(v);
      }
    }
  }
}

// ---------------- attention: one block per (b,h); S=77 padded to 80 ----------------
__global__ __launch_bounds__(256) void attn_k(const u16* __restrict__ qkv, u16* __restrict__ ctx) {
  __shared__ u16 sQK[10240];        // sQ[80][64] @0, sK[80][64] @5120; later reused as sP[80][96]
  __shared__ u16 sVt[64 * 120];     // V transposed [d][k], stride 120
  __shared__ float sS[80][81];      // scores fp32
  const int tid = threadIdx.x;
  const int lane = tid & 63;
  const int wv = tid >> 6;
  const int b = blockIdx.x / 12;
  const int h = blockIdx.x % 12;
  u16* sQ = sQK;
  u16* sK = sQK + 5120;
  u16* sP = sQK;

  for (int i = tid; i < 10240 + 64 * 120; i += 256) {
    if (i < 10240) sQK[i] = 0; else sVt[i - 10240] = 0;
  }
  __syncthreads();

  const size_t tokBase = (size_t)(b * 77) * 2304 + h * 64;
  for (int c = tid; c < 77 * 8; c += 256) {
    const int row = c >> 3, k8 = (c & 7) * 8;
    const size_t src = tokBase + (size_t)row * 2304 + k8;
    *(u16x8*)&sQ[row * 64 + k8] = *(const u16x8*)&qkv[src];
    *(u16x8*)&sK[row * 64 + k8] = *(const u16x8*)&qkv[src + 768];
    u16x8 v = *(const u16x8*)&qkv[src + 1536];
#pragma unroll
    for (int j = 0; j < 8; ++j) sVt[(k8 + j) * 120 + row] = v[j];
  }
  __syncthreads();

  const int frow = lane & 15, fk = (lane >> 4) * 8;
  for (int t = wv; t < 25; t += 4) {
    const int it = t / 5, jt = t % 5;
    v4f acc = {0.f, 0.f, 0.f, 0.f};
#pragma unroll
    for (int kk = 0; kk < 2; ++kk) {
      v8bf a = *(const v8bf*)&sQ[(it * 16 + frow) * 64 + kk * 32 + fk];
      v8bf bb = *(const v8bf*)&sK[(jt * 16 + frow) * 64 + kk * 32 + fk];
      acc = MF(a, bb, acc);
    }
    const int col = jt * 16 + frow;
#pragma unroll
    for (int r = 0; r < 4; ++r) {
      const int row = it * 16 + (lane >> 4) * 4 + r;
      sS[row][col] = (col > row) ? -1e30f : acc[r];
    }
  }
  __syncthreads();

  if (tid < 80) {
    const int row = tid;
    float mx = -1e30f;
    for (int c2 = 0; c2 < 80; ++c2) mx = fmaxf(mx, sS[row][c2]);
    float sum = 0.f;
    for (int c2 = 0; c2 < 80; ++c2) { float e = __expf(sS[row][c2] - mx); sum += e; sS[row][c2] = e; }
    const float inv = 1.f / sum;
    for (int c2 = 0; c2 < 80; ++c2) sP[row * 96 + c2] = f2bf(sS[row][c2] * inv);
    for (int c2 = 80; c2 < 96; ++c2) sP[row * 96 + c2] = 0;
  }
  __syncthreads();

  const size_t outBase = (size_t)(b * 77) * 768 + h * 64;
  for (int t = wv; t < 20; t += 4) {
    const int it = t / 4, jt = t % 4;
    v4f acc = {0.f, 0.f, 0.f, 0.f};
#pragma unroll
    for (int kk = 0; kk < 3; ++kk) {
      v8bf a = *(const v8bf*)&sP[(it * 16 + frow) * 96 + kk * 32 + fk];
      v8bf bb = *(const v8bf*)&sVt[(jt * 16 + frow) * 120 + kk * 32 + fk];
      acc = MF(a, bb, acc);
    }
    const int col = jt * 16 + frow;
#pragma unroll
    for (int r = 0; r < 4; ++r) {
      const int row = it * 16 + (lane >> 4) * 4 + r;
      if (row < 77) ctx[outBase + (size_t)row * 768 + col] = f2bf(acc[r]);
    }
  }
}

// ---------------- launch ----------------
extern "C" void kernel_launch(void* const* d_in, const int* in_sizes, int n_in,
                              void* d_out, int out_size, void* d_ws, size_t ws_size,
                              hipStream_t stream) {
  const float* x    = (const float*)d_in[0];
  const float* ln1w = (const float*)d_in[1];
  const float* ln1b = (const float*)d_in[2];
  const float* qw   = (const float*)d_in[3];
  const float* qb   = (const float*)d_in[4];
  const float* kw   = (const float*)d_in[5];
  const float* kb   = (const float*)d_in[6];
  const float* vw   = (const float*)d_in[7];
  const float* vb   = (const float*)d_in[8];
  const float* ow   = (const float*)d_in[9];
  const float* ob   = (const float*)d_in[10];
  const float* ln2w = (const float*)d_in[11];
  const float* ln2b = (const float*)d_in[12];
  const float* f1wf = (const float*)d_in[13];
  const float* f1b  = (const float*)d_in[14];
  const float* f2wf = (const float*)d_in[15];
  const float* f2b  = (const float*)d_in[16];
  float* outp = (float*)d_out;

  char* p = (char*)d_ws;
  auto alloc = [&](size_t bytes) { char* r = p; p += (bytes + 255) & ~(size_t)255; return r; };
  u16* wqkv = (u16*)alloc((size_t)2304 * 768 * 2);   // rows: qw*0.125 | kw | vw
  u16* owb  = (u16*)alloc((size_t)768 * 768 * 2);
  u16* f1w  = (u16*)alloc((size_t)3072 * 768 * 2);
  u16* f2w  = (u16*)alloc((size_t)768 * 3072 * 2);
  float* qkvb = (float*)alloc(2304 * 4);
  u16* bufA = (u16*)alloc((size_t)M_TOK * 768 * 2);   // h -> ctx -> h2in
  u16* bufB = (u16*)alloc((size_t)M_TOK * 3072 * 2);  // qkv (2304 cols) -> h2 (3072 cols)

  cvt4_k<<<576, 256, 0, stream>>>(qw, wqkv, 147456, 0.125f);
  cvt4_k<<<576, 256, 0, stream>>>(kw, wqkv + 589824, 147456, 1.f);
  cvt4_k<<<576, 256, 0, stream>>>(vw, wqkv + 1179648, 147456, 1.f);
  cvt4_k<<<576, 256, 0, stream>>>(ow, owb, 147456, 1.f);
  cvt4_k<<<2304, 256, 0, stream>>>(f1wf, f1w, 589824, 1.f);
  cvt4_k<<<2304, 256, 0, stream>>>(f2wf, f2w, 589824, 1.f);
  qkvb_k<<<9, 256, 0, stream>>>(qb, kb, vb, qkvb);

  ln_k<<<M_TOK / 4, 256, 0, stream>>>(x, ln1w, ln1b, bufA, M_TOK);
  gemm_k<0, 0, 0><<<308 * 9, 512, 0, stream>>>(bufA, wqkv, qkvb, nullptr, bufB, M_TOK, 2304, 768, 9);
  attn_k<<<512 * 12, 256, 0, stream>>>(bufB, bufA);
  gemm_k<1, 0, 1><<<308 * 3, 512, 0, stream>>>(bufA, owb, ob, x, outp, M_TOK, 768, 768, 3);
  ln_k<<<M_TOK / 4, 256, 0, stream>>>(outp, ln2w, ln2b, bufA, M_TOK);
  gemm_k<0, 1, 0><<<308 * 12, 512, 0, stream>>>(bufA, f1w, f1b, nullptr, bufB, M_TOK, 3072, 768, 12);
  gemm_k<1, 0, 1><<<308 * 3, 512, 0, stream>>>(bufB, f2w, f2b, outp, outp, M_TOK, 768, 3072, 3);
}

// Round 5
// 955.114 us; speedup vs baseline: 1.0797x; 1.0130x over previous
//
#include <hip/hip_runtime.h>

typedef unsigned short u16;
typedef __bf16 v8bf __attribute__((ext_vector_type(8)));
typedef unsigned short u16x8 __attribute__((ext_vector_type(8)));
typedef float v4f __attribute__((ext_vector_type(4)));

#define DEV __device__ __forceinline__

constexpr int M_TOK = 512 * 77;   // 39424 = 256*154

DEV u16 f2bf(float f) {
  union { float f; unsigned int u; } v; v.f = f;
  unsigned int r = v.u + 0x7fffu + ((v.u >> 16) & 1u);
  return (u16)(r >> 16);
}

DEV void gload16(const void* g, void* l) {
  __builtin_amdgcn_global_load_lds((const __attribute__((address_space(1))) void*)g,
                                   (__attribute__((address_space(3))) void*)l, 16, 0, 0);
}

DEV v4f MF(v8bf a, v8bf b, v4f c) {
  return __builtin_amdgcn_mfma_f32_16x16x32_bf16(a, b, c, 0, 0, 0);
}

// ---------------- fp32 -> bf16 convert (x4 vectorized), optional scale ----------------
__global__ void cvt4_k(const float* __restrict__ src, u16* __restrict__ dst, int n4, float scale) {
  int i = blockIdx.x * blockDim.x + threadIdx.x;
  if (i >= n4) return;
  const float4 v = ((const float4*)src)[i];
  ushort4 o;
  o.x = f2bf(v.x * scale); o.y = f2bf(v.y * scale);
  o.z = f2bf(v.z * scale); o.w = f2bf(v.w * scale);
  ((ushort4*)dst)[i] = o;
}

__global__ void qkvb_k(const float* __restrict__ qb, const float* __restrict__ kb,
                       const float* __restrict__ vb, float* __restrict__ dst) {
  int i = blockIdx.x * 256 + threadIdx.x;
  if (i >= 2304) return;
  dst[i] = (i < 768) ? qb[i] * 0.125f : (i < 1536 ? kb[i - 768] : vb[i - 1536]);
}

// ---------------- LayerNorm: one wave per row of 768, writes bf16 ----------------
__global__ __launch_bounds__(256) void ln_k(const float* __restrict__ x, const float* __restrict__ w,
                                            const float* __restrict__ bvec, u16* __restrict__ out, int nrows) {
  const int lane = threadIdx.x & 63;
  const int row = blockIdx.x * 4 + (threadIdx.x >> 6);
  if (row >= nrows) return;
  const float4* xr = (const float4*)(x + (size_t)row * 768);
  float4 v[3];
  float sum = 0.f, sq = 0.f;
#pragma unroll
  for (int t = 0; t < 3; ++t) {
    v[t] = xr[lane + 64 * t];
    sum += v[t].x + v[t].y + v[t].z + v[t].w;
    sq  += v[t].x * v[t].x + v[t].y * v[t].y + v[t].z * v[t].z + v[t].w * v[t].w;
  }
#pragma unroll
  for (int o = 1; o < 64; o <<= 1) { sum += __shfl_xor(sum, o, 64); sq += __shfl_xor(sq, o, 64); }
  const float mean = sum * (1.f / 768.f);
  const float inv = rsqrtf(sq * (1.f / 768.f) - mean * mean + 1e-5f);
  u16* orow = out + (size_t)row * 768;
#pragma unroll
  for (int t = 0; t < 3; ++t) {
    const int c = 4 * (lane + 64 * t);
    ushort4 o4;
    o4.x = f2bf((v[t].x - mean) * inv * w[c + 0] + bvec[c + 0]);
    o4.y = f2bf((v[t].y - mean) * inv * w[c + 1] + bvec[c + 1]);
    o4.z = f2bf((v[t].z - mean) * inv * w[c + 2] + bvec[c + 2]);
    o4.w = f2bf((v[t].w - mean) * inv * w[c + 3] + bvec[c + 3]);
    *(ushort4*)(orow + c) = o4;
  }
}

// ---------------- GEMM: m201-style 256x256 tile, BK=64, 8 waves (128x64 each) ----------
// out[M][N] = act(A[M][K](bf16) @ B[N][K]^T(bf16) + bias) [+res]
// LDS: 2 bufs x (A[256][64] + B[256][64]) bf16 = 2 x 64KB = 128KB, 1 block/CU.
// Swizzle: row granule gr holds k-chunk gr^(row&7) (applied on global src AND ds_read).
// 8 phases / K-tile pair; 2 quarter-stages per phase in consumption order
// [A0,A2,B0,B1,B2,B3,A1,A3]; vmcnt(2) before the closing barrier of ph1/ph4/ph5/ph8.
template <int OUTF32, int ACT, int RES>
__global__ __launch_bounds__(512, 2) void gemm256_k(
    const u16* __restrict__ A, const u16* __restrict__ Bw,
    const float* __restrict__ bias, const float* __restrict__ res,
    void* __restrict__ out, int M, int N, int K, int nbx) {
  __shared__ u16 lds[65536];
  const int tid = threadIdx.x;
  const int lane = tid & 63;
  const int wv = tid >> 6;
  const int wr = wv >> 2, wc = wv & 3;   // wave tile: 128(M) x 64(N)

  // bijective XCD swizzle (m204 form), m-outer
  const int nwg = gridDim.x;
  const int q8 = nwg >> 3, r8 = nwg & 7;
  const int xcd = blockIdx.x & 7, cidx = blockIdx.x >> 3;
  const int wg = (xcd < r8 ? xcd * (q8 + 1) : r8 * (q8 + 1) + (xcd - r8) * q8) + cidx;
  const int m0 = (wg / nbx) * 256;
  const int n0 = (wg % nbx) * 256;

  const int frow = lane & 15, fq = lane >> 4;
  const int e = frow & 7;
  // ds_read bases (u16 idx): kk=0 chunk = fq^e ; kk=1 chunk = (fq^e)^4 -> base^32
  const int aB0 = wr * 8192 + frow * 64 + ((fq ^ e) * 8);
  const int aB1 = aB0 ^ 32;
  const int bB0 = 16384 + wc * 4096 + frow * 64 + ((fq ^ e) * 8);
  const int bB1 = bB0 ^ 32;

  // staging: thread tid -> granule tid of a quarter (64 rows x 8 granules); pre-swizzled src
  const int srow = tid >> 3;
  const int cOff = ((tid & 7) ^ (srow & 7)) * 8;
  const u16* pA = A + (size_t)(m0 + srow) * K + cOff;
  const u16* pB = Bw + (size_t)(n0 + srow) * K + cOff;
  const size_t qk = (size_t)K * 64;   // one quarter's row span in elems
  const int ldsW = wv * 512;          // wave-uniform dest; HW adds lane*16B

#define LD(IDX) (*(const v8bf*)&lds[IDX])
#define BAR() asm volatile("s_barrier" ::: "memory")
#define VM2() asm volatile("s_waitcnt vmcnt(2)" ::: "memory")
#define VM0() asm volatile("s_waitcnt vmcnt(0)" ::: "memory")
#define P1() __builtin_amdgcn_s_setprio(1)
#define P0() __builtin_amdgcn_s_setprio(0)
#define MM4(ii) acc[ii][0] = MF(fa##ii, fb0, acc[ii][0]); \
                acc[ii][1] = MF(fa##ii, fb1, acc[ii][1]); \
                acc[ii][2] = MF(fa##ii, fb2, acc[ii][2]); \
                acc[ii][3] = MF(fa##ii, fb3, acc[ii][3])

  v4f acc[8][4];
#pragma unroll
  for (int i = 0; i < 8; ++i)
#pragma unroll
    for (int j = 0; j < 4; ++j) acc[i][j] = (v4f){0.f, 0.f, 0.f, 0.f};

  const int NT = K >> 6;   // 12 or 48 K-tiles (even)

  // prologue: stage tile 0 -> buf0, order [A0,A2,B0,B1,B2,B3,A1,A3]
  gload16(pA + 0 * qk, &lds[0 + ldsW]);
  gload16(pA + 2 * qk, &lds[8192 + ldsW]);
  gload16(pB + 0 * qk, &lds[16384 + ldsW]);
  gload16(pB + 1 * qk, &lds[20480 + ldsW]);
  gload16(pB + 2 * qk, &lds[24576 + ldsW]);
  gload16(pB + 3 * qk, &lds[28672 + ldsW]);
  gload16(pA + 1 * qk, &lds[4096 + ldsW]);
  gload16(pA + 3 * qk, &lds[12288 + ldsW]);
  VM2(); BAR();

  for (int kt = 0; kt < NT; kt += 2) {
    const u16* PA1 = pA + (size_t)(kt + 1) * 64;
    const u16* PB1 = pB + (size_t)(kt + 1) * 64;
    const u16* PA2 = PA1 + 64;
    const u16* PB2 = PB1 + 64;
    const int STG2 = (kt + 2 < NT);
    v8bf fa0, fa1, fa2, fa3, fa4, fa5, fa6, fa7, fb0, fb1, fb2, fb3;

    // ===== ph1: buf0 kk0, A i0-3 + B j0-3; stage kt+1 A0,A2 -> buf1 =====
    fb0 = LD(bB0); fb1 = LD(bB0 + 1024); fb2 = LD(bB0 + 2048); fb3 = LD(bB0 + 3072);
    fa0 = LD(aB0); fa1 = LD(aB0 + 1024); fa2 = LD(aB0 + 2048); fa3 = LD(aB0 + 3072);
    gload16(PA1 + 0 * qk, &lds[32768 + 0 + ldsW]);
    gload16(PA1 + 2 * qk, &lds[32768 + 8192 + ldsW]);
    VM2(); BAR();
    P1(); MM4(0); MM4(1); MM4(2); MM4(3); P0(); BAR();
    // ===== ph2: buf0 kk0, A i4-7 (B regs reused); stage B0,B1 =====
    fa4 = LD(aB0 + 4096); fa5 = LD(aB0 + 5120); fa6 = LD(aB0 + 6144); fa7 = LD(aB0 + 7168);
    gload16(PB1 + 0 * qk, &lds[32768 + 16384 + ldsW]);
    gload16(PB1 + 1 * qk, &lds[32768 + 20480 + ldsW]);
    BAR();
    P1(); MM4(4); MM4(5); MM4(6); MM4(7); P0(); BAR();
    // ===== ph3: buf0 kk1, A i0-3 + B j0-3; stage B2,B3 =====
    fb0 = LD(bB1); fb1 = LD(bB1 + 1024); fb2 = LD(bB1 + 2048); fb3 = LD(bB1 + 3072);
    fa0 = LD(aB1); fa1 = LD(aB1 + 1024); fa2 = LD(aB1 + 2048); fa3 = LD(aB1 + 3072);
    gload16(PB1 + 2 * qk, &lds[32768 + 24576 + ldsW]);
    gload16(PB1 + 3 * qk, &lds[32768 + 28672 + ldsW]);
    BAR();
    P1(); MM4(0); MM4(1); MM4(2); MM4(3); P0(); BAR();
    // ===== ph4: buf0 kk1, A i4-7; stage A1,A3 =====
    fa4 = LD(aB1 + 4096); fa5 = LD(aB1 + 5120); fa6 = LD(aB1 + 6144); fa7 = LD(aB1 + 7168);
    gload16(PA1 + 1 * qk, &lds[32768 + 4096 + ldsW]);
    gload16(PA1 + 3 * qk, &lds[32768 + 12288 + ldsW]);
    VM2(); BAR();
    P1(); MM4(4); MM4(5); MM4(6); MM4(7); P0(); BAR();
    // ===== ph5: buf1 kk0, A i0-3 + B j0-3; stage kt+2 A0,A2 -> buf0 =====
    fb0 = LD(32768 + bB0); fb1 = LD(32768 + bB0 + 1024); fb2 = LD(32768 + bB0 + 2048); fb3 = LD(32768 + bB0 + 3072);
    fa0 = LD(32768 + aB0); fa1 = LD(32768 + aB0 + 1024); fa2 = LD(32768 + aB0 + 2048); fa3 = LD(32768 + aB0 + 3072);
    if (STG2) {
      gload16(PA2 + 0 * qk, &lds[0 + ldsW]);
      gload16(PA2 + 2 * qk, &lds[8192 + ldsW]);
      VM2();
    } else {
      VM0();
    }
    BAR();
    P1(); MM4(0); MM4(1); MM4(2); MM4(3); P0(); BAR();
    // ===== ph6: buf1 kk0, A i4-7; stage B0,B1 =====
    fa4 = LD(32768 + aB0 + 4096); fa5 = LD(32768 + aB0 + 5120); fa6 = LD(32768 + aB0 + 6144); fa7 = LD(32768 + aB0 + 7168);
    if (STG2) {
      gload16(PB2 + 0 * qk, &lds[16384 + ldsW]);
      gload16(PB2 + 1 * qk, &lds[20480 + ldsW]);
    }
    BAR();
    P1(); MM4(4); MM4(5); MM4(6); MM4(7); P0(); BAR();
    // ===== ph7: buf1 kk1, A i0-3 + B j0-3; stage B2,B3 =====
    fb0 = LD(32768 + bB1); fb1 = LD(32768 + bB1 + 1024); fb2 = LD(32768 + bB1 + 2048); fb3 = LD(32768 + bB1 + 3072);
    fa0 = LD(32768 + aB1); fa1 = LD(32768 + aB1 + 1024); fa2 = LD(32768 + aB1 + 2048); fa3 = LD(32768 + aB1 + 3072);
    if (STG2) {
      gload16(PB2 + 2 * qk, &lds[24576 + ldsW]);
      gload16(PB2 + 3 * qk, &lds[28672 + ldsW]);
    }
    BAR();
    P1(); MM4(0); MM4(1); MM4(2); MM4(3); P0(); BAR();
    // ===== ph8: buf1 kk1, A i4-7; stage A1,A3 =====
    fa4 = LD(32768 + aB1 + 4096); fa5 = LD(32768 + aB1 + 5120); fa6 = LD(32768 + aB1 + 6144); fa7 = LD(32768 + aB1 + 7168);
    if (STG2) {
      gload16(PA2 + 1 * qk, &lds[4096 + ldsW]);
      gload16(PA2 + 3 * qk, &lds[12288 + ldsW]);
      VM2();
    }
    BAR();
    P1(); MM4(4); MM4(5); MM4(6); MM4(7); P0(); BAR();
  }
#undef LD
#undef BAR
#undef VM2
#undef VM0
#undef P1
#undef P0
#undef MM4

  // epilogue: C/D layout col=lane&15, row=(lane>>4)*4+rr
#pragma unroll
  for (int i = 0; i < 8; ++i) {
    const int rowb = m0 + wr * 128 + i * 16 + fq * 4;
#pragma unroll
    for (int j = 0; j < 4; ++j) {
      const int col = n0 + wc * 64 + j * 16 + frow;
      const float bv = bias[col];
#pragma unroll
      for (int rr = 0; rr < 4; ++rr) {
        float v = acc[i][j][rr] + bv;
        if (ACT) v = v * (1.f / (1.f + __expf(-1.702f * v)));  // QuickGELU
        const size_t off = (size_t)(rowb + rr) * N + col;
        if (RES) v += res[off];
        if (OUTF32) ((float*)out)[off] = v;
        else ((u16*)out)[off] = f2bf(v);
      }
    }
  }
}

// ---------------- attention: one block per (b,h); S=77 padded to 80 ----------------
__global__ __launch_bounds__(256) void attn_k(const u16* __restrict__ qkv, u16* __restrict__ ctx) {
  __shared__ u16 sQK[10240];        // sQ[80][64] @0, sK[80][64] @5120; later reused as sP[80][96]
  __shared__ u16 sVt[64 * 120];     // V transposed [d][k], stride 120
  __shared__ float sS[80][81];      // scores fp32
  const int tid = threadIdx.x;
  const int lane = tid & 63;
  const int wv = tid >> 6;
  const int b = blockIdx.x / 12;
  const int h = blockIdx.x % 12;
  u16* sQ = sQK;
  u16* sK = sQK + 5120;
  u16* sP = sQK;

  for (int i = tid; i < 10240 + 64 * 120; i += 256) {
    if (i < 10240) sQK[i] = 0; else sVt[i - 10240] = 0;
  }
  __syncthreads();

  const size_t tokBase = (size_t)(b * 77) * 2304 + h * 64;
  for (int c = tid; c < 77 * 8; c += 256) {
    const int row = c >> 3, k8 = (c & 7) * 8;
    const size_t src = tokBase + (size_t)row * 2304 + k8;
    *(u16x8*)&sQ[row * 64 + k8] = *(const u16x8*)&qkv[src];
    *(u16x8*)&sK[row * 64 + k8] = *(const u16x8*)&qkv[src + 768];
    u16x8 v = *(const u16x8*)&qkv[src + 1536];
#pragma unroll
    for (int j = 0; j < 8; ++j) sVt[(k8 + j) * 120 + row] = v[j];
  }
  __syncthreads();

  const int frow = lane & 15, fk = (lane >> 4) * 8;
  for (int t = wv; t < 25; t += 4) {
    const int it = t / 5, jt = t % 5;
    v4f acc = {0.f, 0.f, 0.f, 0.f};
#pragma unroll
    for (int kk = 0; kk < 2; ++kk) {
      v8bf a = *(const v8bf*)&sQ[(it * 16 + frow) * 64 + kk * 32 + fk];
      v8bf bb = *(const v8bf*)&sK[(jt * 16 + frow) * 64 + kk * 32 + fk];
      acc = MF(a, bb, acc);
    }
    const int col = jt * 16 + frow;
#pragma unroll
    for (int r = 0; r < 4; ++r) {
      const int row = it * 16 + (lane >> 4) * 4 + r;
      sS[row][col] = (col > row) ? -1e30f : acc[r];
    }
  }
  __syncthreads();

  if (tid < 80) {
    const int row = tid;
    float mx = -1e30f;
    for (int c2 = 0; c2 < 80; ++c2) mx = fmaxf(mx, sS[row][c2]);
    float sum = 0.f;
    for (int c2 = 0; c2 < 80; ++c2) { float e = __expf(sS[row][c2] - mx); sum += e; sS[row][c2] = e; }
    const float inv = 1.f / sum;
    for (int c2 = 0; c2 < 80; ++c2) sP[row * 96 + c2] = f2bf(sS[row][c2] * inv);
    for (int c2 = 80; c2 < 96; ++c2) sP[row * 96 + c2] = 0;
  }
  __syncthreads();

  const size_t outBase = (size_t)(b * 77) * 768 + h * 64;
  for (int t = wv; t < 20; t += 4) {
    const int it = t / 4, jt = t % 4;
    v4f acc = {0.f, 0.f, 0.f, 0.f};
#pragma unroll
    for (int kk = 0; kk < 3; ++kk) {
      v8bf a = *(const v8bf*)&sP[(it * 16 + frow) * 96 + kk * 32 + fk];
      v8bf bb = *(const v8bf*)&sVt[(jt * 16 + frow) * 120 + kk * 32 + fk];
      acc = MF(a, bb, acc);
    }
    const int col = jt * 16 + frow;
#pragma unroll
    for (int r = 0; r < 4; ++r) {
      const int row = it * 16 + (lane >> 4) * 4 + r;
      if (row < 77) ctx[outBase + (size_t)row * 768 + col] = f2bf(acc[r]);
    }
  }
}

// ---------------- launch ----------------
extern "C" void kernel_launch(void* const* d_in, const int* in_sizes, int n_in,
                              void* d_out, int out_size, void* d_ws, size_t ws_size,
                              hipStream_t stream) {
  const float* x    = (const float*)d_in[0];
  const float* ln1w = (const float*)d_in[1];
  const float* ln1b = (const float*)d_in[2];
  const float* qw   = (const float*)d_in[3];
  const float* qb   = (const float*)d_in[4];
  const float* kw   = (const float*)d_in[5];
  const float* kb   = (const float*)d_in[6];
  const float* vw   = (const float*)d_in[7];
  const float* vb   = (const float*)d_in[8];
  const float* ow   = (const float*)d_in[9];
  const float* ob   = (const float*)d_in[10];
  const float* ln2w = (const float*)d_in[11];
  const float* ln2b = (const float*)d_in[12];
  const float* f1wf = (const float*)d_in[13];
  const float* f1b  = (const float*)d_in[14];
  const float* f2wf = (const float*)d_in[15];
  const float* f2b  = (const float*)d_in[16];
  float* outp = (float*)d_out;

  char* p = (char*)d_ws;
  auto alloc = [&](size_t bytes) { char* r = p; p += (bytes + 255) & ~(size_t)255; return r; };
  u16* wqkv = (u16*)alloc((size_t)2304 * 768 * 2);   // rows: qw*0.125 | kw | vw
  u16* owb  = (u16*)alloc((size_t)768 * 768 * 2);
  u16* f1w  = (u16*)alloc((size_t)3072 * 768 * 2);
  u16* f2w  = (u16*)alloc((size_t)768 * 3072 * 2);
  float* qkvb = (float*)alloc(2304 * 4);
  u16* bufA = (u16*)alloc((size_t)M_TOK * 768 * 2);   // h -> ctx -> h2in
  u16* bufB = (u16*)alloc((size_t)M_TOK * 3072 * 2);  // qkv (2304 cols) -> h2 (3072 cols)

  cvt4_k<<<576, 256, 0, stream>>>(qw, wqkv, 147456, 0.125f);
  cvt4_k<<<576, 256, 0, stream>>>(kw, wqkv + 589824, 147456, 1.f);
  cvt4_k<<<576, 256, 0, stream>>>(vw, wqkv + 1179648, 147456, 1.f);
  cvt4_k<<<576, 256, 0, stream>>>(ow, owb, 147456, 1.f);
  cvt4_k<<<2304, 256, 0, stream>>>(f1wf, f1w, 589824, 1.f);
  cvt4_k<<<2304, 256, 0, stream>>>(f2wf, f2w, 589824, 1.f);
  qkvb_k<<<9, 256, 0, stream>>>(qb, kb, vb, qkvb);

  ln_k<<<M_TOK / 4, 256, 0, stream>>>(x, ln1w, ln1b, bufA, M_TOK);
  gemm256_k<0, 0, 0><<<154 * 9, 512, 0, stream>>>(bufA, wqkv, qkvb, nullptr, bufB, M_TOK, 2304, 768, 9);
  attn_k<<<512 * 12, 256, 0, stream>>>(bufB, bufA);
  gemm256_k<1, 0, 1><<<154 * 3, 512, 0, stream>>>(bufA, owb, ob, x, outp, M_TOK, 768, 768, 3);
  ln_k<<<M_TOK / 4, 256, 0, stream>>>(outp, ln2w, ln2b, bufA, M_TOK);
  gemm256_k<0, 1, 0><<<154 * 12, 512, 0, stream>>>(bufA, f1w, f1b, nullptr, bufB, M_TOK, 3072, 768, 12);
  gemm256_k<1, 0, 1><<<154 * 3, 512, 0, stream>>>(bufB, f2w, f2b, outp, outp, M_TOK, 768, 3072, 3);
}

// Round 6
// 906.160 us; speedup vs baseline: 1.1381x; 1.0540x over previous
//
#include <hip/hip_runtime.h>

typedef unsigned short u16;
typedef __bf16 v8bf __attribute__((ext_vector_type(8)));
typedef unsigned short u16x8 __attribute__((ext_vector_type(8)));
typedef float v4f __attribute__((ext_vector_type(4)));

#define DEV __device__ __forceinline__

constexpr int M_TOK = 512 * 77;   // 39424 = 256*154

DEV u16 f2bf(float f) {
  union { float f; unsigned int u; } v; v.f = f;
  unsigned int r = v.u + 0x7fffu + ((v.u >> 16) & 1u);
  return (u16)(r >> 16);
}

DEV void gload16(const void* g, void* l) {
  __builtin_amdgcn_global_load_lds((const __attribute__((address_space(1))) void*)g,
                                   (__attribute__((address_space(3))) void*)l, 16, 0, 0);
}

DEV v4f MF(v8bf a, v8bf b, v4f c) {
  return __builtin_amdgcn_mfma_f32_16x16x32_bf16(a, b, c, 0, 0, 0);
}

// ---------------- fp32 -> bf16 convert (x4 vectorized), optional scale ----------------
__global__ void cvt4_k(const float* __restrict__ src, u16* __restrict__ dst, int n4, float scale) {
  int i = blockIdx.x * blockDim.x + threadIdx.x;
  if (i >= n4) return;
  const float4 v = ((const float4*)src)[i];
  ushort4 o;
  o.x = f2bf(v.x * scale); o.y = f2bf(v.y * scale);
  o.z = f2bf(v.z * scale); o.w = f2bf(v.w * scale);
  ((ushort4*)dst)[i] = o;
}

__global__ void qkvb_k(const float* __restrict__ qb, const float* __restrict__ kb,
                       const float* __restrict__ vb, float* __restrict__ dst) {
  int i = blockIdx.x * 256 + threadIdx.x;
  if (i >= 2304) return;
  dst[i] = (i < 768) ? qb[i] * 0.125f : (i < 1536 ? kb[i - 768] : vb[i - 1536]);
}

// ---------------- LayerNorm: one wave per row of 768, writes bf16 ----------------
__global__ __launch_bounds__(256) void ln_k(const float* __restrict__ x, const float* __restrict__ w,
                                            const float* __restrict__ bvec, u16* __restrict__ out, int nrows) {
  const int lane = threadIdx.x & 63;
  const int row = blockIdx.x * 4 + (threadIdx.x >> 6);
  if (row >= nrows) return;
  const float4* xr = (const float4*)(x + (size_t)row * 768);
  float4 v[3];
  float sum = 0.f, sq = 0.f;
#pragma unroll
  for (int t = 0; t < 3; ++t) {
    v[t] = xr[lane + 64 * t];
    sum += v[t].x + v[t].y + v[t].z + v[t].w;
    sq  += v[t].x * v[t].x + v[t].y * v[t].y + v[t].z * v[t].z + v[t].w * v[t].w;
  }
#pragma unroll
  for (int o = 1; o < 64; o <<= 1) { sum += __shfl_xor(sum, o, 64); sq += __shfl_xor(sq, o, 64); }
  const float mean = sum * (1.f / 768.f);
  const float inv = rsqrtf(sq * (1.f / 768.f) - mean * mean + 1e-5f);
  u16* orow = out + (size_t)row * 768;
#pragma unroll
  for (int t = 0; t < 3; ++t) {
    const int c = 4 * (lane + 64 * t);
    ushort4 o4;
    o4.x = f2bf((v[t].x - mean) * inv * w[c + 0] + bvec[c + 0]);
    o4.y = f2bf((v[t].y - mean) * inv * w[c + 1] + bvec[c + 1]);
    o4.z = f2bf((v[t].z - mean) * inv * w[c + 2] + bvec[c + 2]);
    o4.w = f2bf((v[t].w - mean) * inv * w[c + 3] + bvec[c + 3]);
    *(ushort4*)(orow + c) = o4;
  }
}

// ---------------- GEMM: 256x256 tile, BK=64, 8 waves (128x64 each), deep-pipelined ----
// out[M][N] = act(A[M][K](bf16) @ B[N][K]^T(bf16) + bias) [+res]
// LDS: 2 bufs x (A[256][64] + B[256][64]) bf16 = 128KB. Swizzle: granule gr of row r
// holds k-chunk gr^(r&7), applied on global src AND ds_read (zero bank conflicts, r5).
// Staging plan (each quarter staged right after its last reader's phase, consumed
// 3-5 phases later; vmcnt(4) at ends of ph8/ph1/ph4/ph5 guards the NEXT phase's reads):
//   ph1: buf1.B0,B1<-kt+1  ph2: buf1.B2,B3  ph3: buf1.A1,A3  ph4: buf0.A0,A2<-kt+2
//   ph5: buf0.B0,B1        ph6: buf0.B2,B3  ph7: buf0.A1,A3  ph8: buf1.A0,A2<-kt+3
template <int OUTF32, int ACT, int RES>
__global__ __launch_bounds__(512, 2) void gemm256_k(
    const u16* __restrict__ A, const u16* __restrict__ Bw,
    const float* __restrict__ bias, const float* __restrict__ res,
    void* __restrict__ out, int M, int N, int K, int nbx) {
  __shared__ u16 lds[65536];
  const int tid = threadIdx.x;
  const int lane = tid & 63;
  const int wv = tid >> 6;
  const int wr = wv >> 2, wc = wv & 3;   // wave tile: 128(M) x 64(N)

  // bijective XCD swizzle (m204 form), m-outer
  const int nwg = gridDim.x;
  const int q8 = nwg >> 3, r8 = nwg & 7;
  const int xcd = blockIdx.x & 7, cidx = blockIdx.x >> 3;
  const int wg = (xcd < r8 ? xcd * (q8 + 1) : r8 * (q8 + 1) + (xcd - r8) * q8) + cidx;
  const int m0 = (wg / nbx) * 256;
  const int n0 = (wg % nbx) * 256;

  const int frow = lane & 15, fq = lane >> 4;
  const int e = frow & 7;
  // ds_read bases (u16 idx): kk=0 chunk = fq^e ; kk=1 chunk = (fq^e)^4 -> base^32
  const int aB0 = wr * 8192 + frow * 64 + ((fq ^ e) * 8);
  const int aB1 = aB0 ^ 32;
  const int bB0 = 16384 + wc * 4096 + frow * 64 + ((fq ^ e) * 8);
  const int bB1 = bB0 ^ 32;

  // staging: thread tid -> granule (tid&7) of row (tid>>3) of a 64-row quarter
  const int srow = tid >> 3;
  const int cOff = ((tid & 7) ^ (srow & 7)) * 8;
  const u16* pA = A + (size_t)(m0 + srow) * K + cOff;
  const u16* pB = Bw + (size_t)(n0 + srow) * K + cOff;
  const size_t qk = (size_t)K * 64;   // one quarter's row span in elems
  const int ldsW = wv * 512;          // wave-uniform dest; HW adds lane*16B

#define LD(IDX) (*(const v8bf*)&lds[IDX])
#define BAR() asm volatile("s_barrier" ::: "memory")
#define VM4() asm volatile("s_waitcnt vmcnt(4)" ::: "memory")
#define VM2() asm volatile("s_waitcnt vmcnt(2)" ::: "memory")
#define VM0() asm volatile("s_waitcnt vmcnt(0)" ::: "memory")
#define P1() __builtin_amdgcn_s_setprio(1)
#define P0() __builtin_amdgcn_s_setprio(0)
#define MM4(ii) acc[ii][0] = MF(fa##ii, fb0, acc[ii][0]); \
                acc[ii][1] = MF(fa##ii, fb1, acc[ii][1]); \
                acc[ii][2] = MF(fa##ii, fb2, acc[ii][2]); \
                acc[ii][3] = MF(fa##ii, fb3, acc[ii][3])
#define RD8(OA, OB) \
  fb0 = LD((OB)); fb1 = LD((OB) + 1024); fb2 = LD((OB) + 2048); fb3 = LD((OB) + 3072); \
  fa0 = LD((OA)); fa1 = LD((OA) + 1024); fa2 = LD((OA) + 2048); fa3 = LD((OA) + 3072)
#define RD4(OA) \
  fa4 = LD((OA) + 4096); fa5 = LD((OA) + 5120); fa6 = LD((OA) + 6144); fa7 = LD((OA) + 7168)
#define MMLO P1(); MM4(0); MM4(1); MM4(2); MM4(3); P0()
#define MMHI P1(); MM4(4); MM4(5); MM4(6); MM4(7); P0()
#define STA(t, g, bof) gload16(pA + (size_t)(g) * qk + (size_t)(t) * 64, \
                               &lds[(bof) + (g) * 4096 + ldsW])
#define STB(t, g, bof) gload16(pB + (size_t)(g) * qk + (size_t)(t) * 64, \
                               &lds[(bof) + 16384 + (g) * 4096 + ldsW])

  v4f acc[8][4];
#pragma unroll
  for (int i = 0; i < 8; ++i)
#pragma unroll
    for (int j = 0; j < 4; ++j) acc[i][j] = (v4f){0.f, 0.f, 0.f, 0.f};

  const int NT = K >> 6;   // 12 or 48 K-tiles (even, >= 4)

  // prologue: buf0 <- tile 0 (consumption order), buf1.A0,A2 <- tile 1
  STA(0, 0, 0); STA(0, 2, 0);
  STB(0, 0, 0); STB(0, 1, 0); STB(0, 2, 0); STB(0, 3, 0);
  STA(0, 1, 0); STA(0, 3, 0);
  STA(1, 0, 32768); STA(1, 2, 32768);
  VM4(); BAR();   // first 6 (A0,A2,B0-B3 of tile 0) landed

  for (int kt = 0; kt < NT - 2; kt += 2) {
    v8bf fa0, fa1, fa2, fa3, fa4, fa5, fa6, fa7, fb0, fb1, fb2, fb3;
    // ph1: buf0 kk0 lo | stage buf1.B0,B1 <- kt+1 | vm4 (guards ph2 reads)
    RD8(aB0, bB0); STB(kt + 1, 0, 32768); STB(kt + 1, 1, 32768);
    VM4(); BAR(); MMLO; BAR();
    // ph2: buf0 kk0 hi | stage buf1.B2,B3
    RD4(aB0); STB(kt + 1, 2, 32768); STB(kt + 1, 3, 32768);
    BAR(); MMHI; BAR();
    // ph3: buf0 kk1 lo | stage buf1.A1,A3
    RD8(aB1, bB1); STA(kt + 1, 1, 32768); STA(kt + 1, 3, 32768);
    BAR(); MMLO; BAR();
    // ph4: buf0 kk1 hi | stage buf0.A0,A2 <- kt+2 | vm4 (guards ph5 reads)
    RD4(aB1); STA(kt + 2, 0, 0); STA(kt + 2, 2, 0);
    VM4(); BAR(); MMHI; BAR();
    // ph5: buf1 kk0 lo | stage buf0.B0,B1 | vm4 (guards ph6 reads)
    RD8(32768 + aB0, 32768 + bB0); STB(kt + 2, 0, 0); STB(kt + 2, 1, 0);
    VM4(); BAR(); MMLO; BAR();
    // ph6: buf1 kk0 hi | stage buf0.B2,B3
    RD4(32768 + aB0); STB(kt + 2, 2, 0); STB(kt + 2, 3, 0);
    BAR(); MMHI; BAR();
    // ph7: buf1 kk1 lo | stage buf0.A1,A3
    RD8(32768 + aB1, 32768 + bB1); STA(kt + 2, 1, 0); STA(kt + 2, 3, 0);
    BAR(); MMLO; BAR();
    // ph8: buf1 kk1 hi | stage buf1.A0,A2 <- kt+3 | vm4 (guards next ph1 reads)
    RD4(32768 + aB1); STA(kt + 3, 0, 32768); STA(kt + 3, 2, 32768);
    VM4(); BAR(); MMHI; BAR();
  }
  {  // peeled last iter: kt = NT-2; only tile NT-1 staging remains (ph1-3)
    const int kt = NT - 2;
    v8bf fa0, fa1, fa2, fa3, fa4, fa5, fa6, fa7, fb0, fb1, fb2, fb3;
    RD8(aB0, bB0); STB(kt + 1, 0, 32768); STB(kt + 1, 1, 32768);
    VM4(); BAR(); MMLO; BAR();
    RD4(aB0); STB(kt + 1, 2, 32768); STB(kt + 1, 3, 32768);
    BAR(); MMHI; BAR();
    RD8(aB1, bB1); STA(kt + 1, 1, 32768); STA(kt + 1, 3, 32768);
    BAR(); MMLO; BAR();
    RD4(aB1); VM2(); BAR(); MMHI; BAR();          // allow only ph3's 2 outstanding
    RD8(32768 + aB0, 32768 + bB0); VM0(); BAR(); MMLO; BAR();  // drain: A1,A3 landed
    RD4(32768 + aB0); BAR(); MMHI; BAR();
    RD8(32768 + aB1, 32768 + bB1); BAR(); MMLO; BAR();
    RD4(32768 + aB1); BAR(); MMHI; BAR();
  }
#undef LD
#undef BAR
#undef VM4
#undef VM2
#undef VM0
#undef P1
#undef P0
#undef MM4
#undef RD8
#undef RD4
#undef MMLO
#undef MMHI
#undef STA
#undef STB

  // epilogue: C/D layout col=lane&15, row=(lane>>4)*4+rr
#pragma unroll
  for (int i = 0; i < 8; ++i) {
    const int rowb = m0 + wr * 128 + i * 16 + fq * 4;
#pragma unroll
    for (int j = 0; j < 4; ++j) {
      const int col = n0 + wc * 64 + j * 16 + frow;
      const float bv = bias[col];
#pragma unroll
      for (int rr = 0; rr < 4; ++rr) {
        float v = acc[i][j][rr] + bv;
        if (ACT) v = v * (1.f / (1.f + __expf(-1.702f * v)));  // QuickGELU
        const size_t off = (size_t)(rowb + rr) * N + col;
        if (RES) v += res[off];
        if (OUTF32) ((float*)out)[off] = v;
        else ((u16*)out)[off] = f2bf(v);
      }
    }
  }
}

// ---------------- attention: one block per (b,h); S=77 padded to 80 ----------------
__global__ __launch_bounds__(256) void attn_k(const u16* __restrict__ qkv, u16* __restrict__ ctx) {
  __shared__ u16 sQK[10240];        // sQ[80][64] @0, sK[80][64] @5120; later reused as sP[80][96]
  __shared__ u16 sVt[64 * 120];     // V transposed [d][k], stride 120
  __shared__ float sS[80][81];      // scores fp32
  const int tid = threadIdx.x;
  const int lane = tid & 63;
  const int wv = tid >> 6;
  const int b = blockIdx.x / 12;
  const int h = blockIdx.x % 12;
  u16* sQ = sQK;
  u16* sK = sQK + 5120;
  u16* sP = sQK;

  for (int i = tid; i < 10240 + 64 * 120; i += 256) {
    if (i < 10240) sQK[i] = 0; else sVt[i - 10240] = 0;
  }
  __syncthreads();

  const size_t tokBase = (size_t)(b * 77) * 2304 + h * 64;
  for (int c = tid; c < 77 * 8; c += 256) {
    const int row = c >> 3, k8 = (c & 7) * 8;
    const size_t src = tokBase + (size_t)row * 2304 + k8;
    *(u16x8*)&sQ[row * 64 + k8] = *(const u16x8*)&qkv[src];
    *(u16x8*)&sK[row * 64 + k8] = *(const u16x8*)&qkv[src + 768];
    u16x8 v = *(const u16x8*)&qkv[src + 1536];
#pragma unroll
    for (int j = 0; j < 8; ++j) sVt[(k8 + j) * 120 + row] = v[j];
  }
  __syncthreads();

  const int frow = lane & 15, fk = (lane >> 4) * 8;
  for (int t = wv; t < 25; t += 4) {
    const int it = t / 5, jt = t % 5;
    v4f acc = {0.f, 0.f, 0.f, 0.f};
#pragma unroll
    for (int kk = 0; kk < 2; ++kk) {
      v8bf a = *(const v8bf*)&sQ[(it * 16 + frow) * 64 + kk * 32 + fk];
      v8bf bb = *(const v8bf*)&sK[(jt * 16 + frow) * 64 + kk * 32 + fk];
      acc = MF(a, bb, acc);
    }
    const int col = jt * 16 + frow;
#pragma unroll
    for (int r = 0; r < 4; ++r) {
      const int row = it * 16 + (lane >> 4) * 4 + r;
      sS[row][col] = (col > row) ? -1e30f : acc[r];
    }
  }
  __syncthreads();

  if (tid < 80) {
    const int row = tid;
    float mx = -1e30f;
    for (int c2 = 0; c2 < 80; ++c2) mx = fmaxf(mx, sS[row][c2]);
    float sum = 0.f;
    for (int c2 = 0; c2 < 80; ++c2) { float e = __expf(sS[row][c2] - mx); sum += e; sS[row][c2] = e; }
    const float inv = 1.f / sum;
    for (int c2 = 0; c2 < 80; ++c2) sP[row * 96 + c2] = f2bf(sS[row][c2] * inv);
    for (int c2 = 80; c2 < 96; ++c2) sP[row * 96 + c2] = 0;
  }
  __syncthreads();

  const size_t outBase = (size_t)(b * 77) * 768 + h * 64;
  for (int t = wv; t < 20; t += 4) {
    const int it = t / 4, jt = t % 4;
    v4f acc = {0.f, 0.f, 0.f, 0.f};
#pragma unroll
    for (int kk = 0; kk < 3; ++kk) {
      v8bf a = *(const v8bf*)&sP[(it * 16 + frow) * 96 + kk * 32 + fk];
      v8bf bb = *(const v8bf*)&sVt[(jt * 16 + frow) * 120 + kk * 32 + fk];
      acc = MF(a, bb, acc);
    }
    const int col = jt * 16 + frow;
#pragma unroll
    for (int r = 0; r < 4; ++r) {
      const int row = it * 16 + (lane >> 4) * 4 + r;
      if (row < 77) ctx[outBase + (size_t)row * 768 + col] = f2bf(acc[r]);
    }
  }
}

// ---------------- launch ----------------
extern "C" void kernel_launch(void* const* d_in, const int* in_sizes, int n_in,
                              void* d_out, int out_size, void* d_ws, size_t ws_size,
                              hipStream_t stream) {
  const float* x    = (const float*)d_in[0];
  const float* ln1w = (const float*)d_in[1];
  const float* ln1b = (const float*)d_in[2];
  const float* qw   = (const float*)d_in[3];
  const float* qb   = (const float*)d_in[4];
  const float* kw   = (const float*)d_in[5];
  const float* kb   = (const float*)d_in[6];
  const float* vw   = (const float*)d_in[7];
  const float* vb   = (const float*)d_in[8];
  const float* ow   = (const float*)d_in[9];
  const float* ob   = (const float*)d_in[10];
  const float* ln2w = (const float*)d_in[11];
  const float* ln2b = (const float*)d_in[12];
  const float* f1wf = (const float*)d_in[13];
  const float* f1b  = (const float*)d_in[14];
  const float* f2wf = (const float*)d_in[15];
  const float* f2b  = (const float*)d_in[16];
  float* outp = (float*)d_out;

  char* p = (char*)d_ws;
  auto alloc = [&](size_t bytes) { char* r = p; p += (bytes + 255) & ~(size_t)255; return r; };
  u16* wqkv = (u16*)alloc((size_t)2304 * 768 * 2);   // rows: qw*0.125 | kw | vw
  u16* owb  = (u16*)alloc((size_t)768 * 768 * 2);
  u16* f1w  = (u16*)alloc((size_t)3072 * 768 * 2);
  u16* f2w  = (u16*)alloc((size_t)768 * 3072 * 2);
  float* qkvb = (float*)alloc(2304 * 4);
  u16* bufA = (u16*)alloc((size_t)M_TOK * 768 * 2);   // h -> ctx -> h2in
  u16* bufB = (u16*)alloc((size_t)M_TOK * 3072 * 2);  // qkv (2304 cols) -> h2 (3072 cols)

  cvt4_k<<<576, 256, 0, stream>>>(qw, wqkv, 147456, 0.125f);
  cvt4_k<<<576, 256, 0, stream>>>(kw, wqkv + 589824, 147456, 1.f);
  cvt4_k<<<576, 256, 0, stream>>>(vw, wqkv + 1179648, 147456, 1.f);
  cvt4_k<<<576, 256, 0, stream>>>(ow, owb, 147456, 1.f);
  cvt4_k<<<2304, 256, 0, stream>>>(f1wf, f1w, 589824, 1.f);
  cvt4_k<<<2304, 256, 0, stream>>>(f2wf, f2w, 589824, 1.f);
  qkvb_k<<<9, 256, 0, stream>>>(qb, kb, vb, qkvb);

  ln_k<<<M_TOK / 4, 256, 0, stream>>>(x, ln1w, ln1b, bufA, M_TOK);
  gemm256_k<0, 0, 0><<<154 * 9, 512, 0, stream>>>(bufA, wqkv, qkvb, nullptr, bufB, M_TOK, 2304, 768, 9);
  attn_k<<<512 * 12, 256, 0, stream>>>(bufB, bufA);
  gemm256_k<1, 0, 1><<<154 * 3, 512, 0, stream>>>(bufA, owb, ob, x, outp, M_TOK, 768, 768, 3);
  ln_k<<<M_TOK / 4, 256, 0, stream>>>(outp, ln2w, ln2b, bufA, M_TOK);
  gemm256_k<0, 1, 0><<<154 * 12, 512, 0, stream>>>(bufA, f1w, f1b, nullptr, bufB, M_TOK, 3072, 768, 12);
  gemm256_k<1, 0, 1><<<154 * 3, 512, 0, stream>>>(bufB, f2w, f2b, outp, outp, M_TOK, 768, 3072, 3);
}